// Round 5
// baseline (3350.643 us; speedup 1.0000x reference)
//
#include <hip/hip_runtime.h>

#define NF 32
#define HDIM 256
#define SLEN 256
#define BATCH 1024

typedef float f32x4 __attribute__((ext_vector_type(4)));
typedef __bf16 bf16x8 __attribute__((ext_vector_type(8)));
typedef unsigned int u32x4 __attribute__((ext_vector_type(4)));
typedef unsigned long long u64;
typedef unsigned short u16;

#define MFMA __builtin_amdgcn_mfma_f32_16x16x32_bf16

// ---- ws layout ----
// uint4 slots [0, 65536): packed MFMA B-fragments
#define WSL_O 0       // W_hh per-slice: p*8192 + (j*8+kt)*64 + l   (32768)
#define WIH_O 32768   // W_ih per-slice: p*1024 + j*64 + l          (4096)
#define WOUT_O 36864  // W_out: (jn*8+kt)*64 + l                    (1024)
#define WLAT_O 37888  // W_lat per-slice: p*1024 + jj*128 + kt*64+l (4096)
#define PREP1_N 41984
#define WT_O 65536    // sigma B frags: ((s*2+jn)*8+kt)*64+l        (262144, 4MB)
// byte offsets
#define THEX_BYTE (5u << 20)   // u64 [64 g][2][4 p][64 c][4 rp]  (1MB)
#define CNT_BYTE  (6u << 20)   // u32 [64 g][257]
#define HST_BYTE  (7u << 20)   // u64 [64 g][257 ss][4 p][64 c][4 rp] (134.7MB)
#define CNT_N (64 * 257)

__device__ __forceinline__ u16 f2bf(float x) {
  union { float f; unsigned int u; } v; v.f = x;
  return (u16)((v.u + 0x7FFFu + ((v.u >> 16) & 1u)) >> 16);
}
__device__ __forceinline__ unsigned int pk2(float a, float b) {
  return (unsigned int)f2bf(a) | ((unsigned int)f2bf(b) << 16);
}
__device__ __forceinline__ float sigf(float x) {
  return __fdividef(1.0f, 1.0f + __expf(-x));
}
__device__ __forceinline__ float tanhf_(float x) {
  return 1.0f - __fdividef(2.0f, __expf(2.0f * x) + 1.0f);
}

// ---------------- prep: pack B-fragments ----------------
__global__ void prep_pack(const float* __restrict__ Whh, const float* __restrict__ Wih,
                          const float* __restrict__ Wout, const float* __restrict__ Wlat,
                          uint4* __restrict__ ws) {
  int i = blockIdx.x * 256 + threadIdx.x;
  if (i >= PREP1_N) return;
  int l = i & 63;
  int c16 = l & 15, g4 = l >> 4;
  const float* src;
  if (i < WIH_O) {                        // W_hh slice frags
    int p = i >> 13, r = i & 8191;
    int j = r >> 9, kt = (r >> 6) & 7;
    int n = (j >> 2) * 256 + p * 64 + (j & 3) * 16 + c16;
    src = Whh + n * 256 + kt * 32 + 8 * g4;
  } else if (i < WOUT_O) {                // W_ih slice frags (K=32)
    int ii = i - WIH_O;
    int p = ii >> 10, j = (ii >> 6) & 15;
    int n = (j >> 2) * 256 + p * 64 + (j & 3) * 16 + c16;
    src = Wih + n * 32 + 8 * g4;
  } else if (i < WLAT_O) {                // W_out frags
    int ii = i - WOUT_O;
    int jn = ii >> 9, kt = (ii >> 6) & 7;
    src = Wout + (jn * 16 + c16) * 256 + kt * 32 + 8 * g4;
  } else {                                // W_lat slice frags (K=64)
    int ii = i - WLAT_O;
    int p = ii >> 10, jj = (ii >> 7) & 7, kt = (ii >> 6) & 1;
    int n = (jj >= 4 ? 256 : 0) + p * 64 + (jj & 3) * 16 + c16;
    src = Wlat + n * 64 + kt * 32 + 8 * g4;
  }
  uint4 P;
  P.x = pk2(src[0], src[1]); P.y = pk2(src[2], src[3]);
  P.z = pk2(src[4], src[5]); P.w = pk2(src[6], src[7]);
  ws[i] = P;
}

// sigma B frags: k-enum (s, h): value = Wsig[f][h*256+s], h = kt*32+8*g4+e
__global__ void prep_wt(const float* __restrict__ Wsig, uint4* __restrict__ ws) {
  int i = blockIdx.x * 256 + threadIdx.x;
  int l = i & 63, kt = (i >> 6) & 7, jn = (i >> 9) & 1, s = i >> 10;
  int f = jn * 16 + (l & 15);
  int h = kt * 32 + 8 * (l >> 4);
  const float* src = Wsig + f * (HDIM * SLEN) + h * 256 + s;
  uint4 P;
  P.x = pk2(src[0 * 256], src[1 * 256]); P.y = pk2(src[2 * 256], src[3 * 256]);
  P.z = pk2(src[4 * 256], src[5 * 256]); P.w = pk2(src[6 * 256], src[7 * 256]);
  ws[WT_O + i] = P;
}

__global__ void prep_zero(unsigned int* __restrict__ cnt) {
  int i = blockIdx.x * 256 + threadIdx.x;
  if (i < CNT_N) cnt[i] = 0;
}

// ---------------- the scan: 256 WGs = 64 groups x 4 gate-slices ----------------
__global__ __launch_bounds__(512, 2) void lstm_scan(
    const float* __restrict__ z, const float* __restrict__ b_lat,
    const float* __restrict__ b_ih, const float* __restrict__ b_hh,
    const float* __restrict__ b_out, const uint4* __restrict__ ws,
    u64* __restrict__ th_ex, unsigned int* __restrict__ cnt,
    u64* __restrict__ hst, float* __restrict__ out) {
  __shared__ __align__(16) uint4 wslb[4096];              // 64KB: W_hh kt0..3
  __shared__ __align__(16) u16 hbuf[16][256];             // 8KB (swizzled)
  __shared__ __align__(16) u16 thbuf[16][256];            // 8KB (swizzled)
  __shared__ __align__(16) u16 xbuf[16][32];              // 1KB
  __shared__ __align__(16) u16 zb[16][64];                // 2KB

  const int tid = threadIdx.x, w = tid >> 6, l = tid & 63;
  const int c16 = l & 15, g4 = l >> 4, r0 = g4 * 4;
  const int wg = blockIdx.x, g = wg >> 2, p = wg & 3;
  const bool isgate = (w < 4);
  const int cb = w & 3;
  const bool isx = (w == 4) || (w == 7);
  const int jn = (w == 7) ? 1 : 0;

  unsigned int* mycnt = cnt + g * 257;

  // one-time: W_hh kt0..3 -> LDS
  for (int i = tid; i < 4096; i += 512) {
    int j = i >> 8, kt = (i >> 6) & 3, ll = i & 63;
    wslb[i] = ws[WSL_O + (p << 13) + ((j << 3) + kt) * 64 + ll];
  }

  // gate-wave persistent regs: W_hh kt4..7 (64 VGPR), W_ih, bias
  u32x4 wr[4][4]; bf16x8 wih[4]; float biasv[4] = {0, 0, 0, 0};
  if (isgate) {
#pragma unroll
    for (int gi = 0; gi < 4; ++gi) {
#pragma unroll
      for (int kk = 0; kk < 4; ++kk)
        wr[gi][kk] = __builtin_bit_cast(u32x4,
            ws[WSL_O + (p << 13) + ((gi * 4 + cb) * 8 + 4 + kk) * 64 + l]);
      wih[gi] = *reinterpret_cast<const bf16x8*>(ws + WIH_O + (p << 10) + (gi * 4 + cb) * 64 + l);
      int n = gi * 256 + p * 64 + cb * 16 + c16;
      biasv[gi] = b_ih[n] + b_hh[n];
    }
#pragma unroll
    for (int gi = 0; gi < 4; ++gi)
#pragma unroll
      for (int kk = 0; kk < 4; ++kk)
        asm volatile("" : "+v"(wr[gi][kk]));  // pin: not rematerializable
  }
  // x-wave persistent regs: W_out frags
  u32x4 wo[8]; float bo = 0.f; f32x4 xacc = {0.f, 0.f, 0.f, 0.f};
  if (isx) {
#pragma unroll
    for (int kt = 0; kt < 8; ++kt)
      wo[kt] = __builtin_bit_cast(u32x4, ws[WOUT_O + (jn * 8 + kt) * 64 + l]);
#pragma unroll
    for (int kt = 0; kt < 8; ++kt) asm volatile("" : "+v"(wo[kt]));
    bo = b_out[jn * 16 + c16];
    xacc = (f32x4){bo, bo, bo, bo};
  }

  // ---- init: hc = z @ W_lat^T + b_lat ----
  for (int idx = tid; idx < 1024; idx += 512) zb[idx >> 6][idx & 63] = f2bf(z[(g * 16 + (idx >> 6)) * 64 + (idx & 63)]);
  if (tid < 512) xbuf[tid >> 5][tid & 31] = 0;
  __syncthreads();

  float cst[4] = {0, 0, 0, 0};
  if (isgate) {
    bf16x8 za0 = *reinterpret_cast<const bf16x8*>(&zb[c16][8 * g4]);
    bf16x8 za1 = *reinterpret_cast<const bf16x8*>(&zb[c16][32 + 8 * g4]);
    int lc = cb * 16 + c16;
    float blh = b_lat[p * 64 + lc];
    float blc = b_lat[256 + p * 64 + lc];
    f32x4 ah = {blh, blh, blh, blh}, ac = {blc, blc, blc, blc};
    const uint4* wl = ws + WLAT_O + (p << 10);
    ah = MFMA(za0, *reinterpret_cast<const bf16x8*>(wl + cb * 128 + l), ah, 0, 0, 0);
    ah = MFMA(za1, *reinterpret_cast<const bf16x8*>(wl + cb * 128 + 64 + l), ah, 0, 0, 0);
    ac = MFMA(za0, *reinterpret_cast<const bf16x8*>(wl + (4 + cb) * 128 + l), ac, 0, 0, 0);
    ac = MFMA(za1, *reinterpret_cast<const bf16x8*>(wl + (4 + cb) * 128 + 64 + l), ac, 0, 0, 0);
    int col = p * 64 + lc;
    u16 hp[4], tp[4];
#pragma unroll
    for (int v = 0; v < 4; ++v) {
      cst[v] = ac[v];
      float hh = ah[v], th = tanhf_(hh);
      int rr = r0 + v, sw = (rr & 7) << 3;
      hp[v] = f2bf(hh); tp[v] = f2bf(th);
      hbuf[rr][col ^ sw] = hp[v]; thbuf[rr][col ^ sw] = tp[v];
    }
    u64 hu = (u64)hp[0] | ((u64)hp[1] << 16) | ((u64)hp[2] << 32) | ((u64)hp[3] << 48);
    u64 tu = (u64)tp[0] | ((u64)tp[1] << 16) | ((u64)tp[2] << 32) | ((u64)tp[3] << 48);
    __hip_atomic_store(&hst[((u64)(g * 257 + 0) * 4 + p) * 256 + lc * 4 + g4], hu,
                       __ATOMIC_RELAXED, __HIP_MEMORY_SCOPE_AGENT);
    __hip_atomic_store(&th_ex[((g * 2 + 0) * 4 + p) * 256 + lc * 4 + g4], tu,
                       __ATOMIC_RELAXED, __HIP_MEMORY_SCOPE_AGENT);
  }
  asm volatile("s_waitcnt vmcnt(0)" ::: "memory");
  __syncthreads();
  if (tid == 0)
    __hip_atomic_fetch_add(&mycnt[0], 1u, __ATOMIC_RELEASE, __HIP_MEMORY_SCOPE_AGENT);

  // ---- the scan ----
  for (int s = 0; s < SLEN; ++s) {
    // P1: poll peers' h_s, th_s
    if (tid == 0) {
      while (__hip_atomic_load(&mycnt[s], __ATOMIC_ACQUIRE, __HIP_MEMORY_SCOPE_AGENT) < 4u)
        __builtin_amdgcn_s_sleep(1);
    }
    __syncthreads();  // B1
    // assemble 3 peers' h,th (1536 u64)
#pragma unroll
    for (int k = 0; k < 3; ++k) {
      int idx = k * 512 + tid;
      bool ih = idx < 768;
      int it = ih ? idx : idx - 768;
      int peer = it >> 8, cr = it & 255;
      int pp = (p + 1 + peer) & 3;
      const u64* src = ih ? &hst[((u64)(g * 257 + s) * 4 + pp) * 256 + cr]
                          : &th_ex[((g * 2 + (s & 1)) * 4 + pp) * 256 + cr];
      u64 v = __hip_atomic_load(src, __ATOMIC_RELAXED, __HIP_MEMORY_SCOPE_AGENT);
      int colg = pp * 64 + (cr >> 2), rb = (cr & 3) * 4;
#pragma unroll
      for (int e = 0; e < 4; ++e) {
        int r = rb + e;
        u16 val = (u16)(v >> (16 * e));
        if (ih) hbuf[r][colg ^ ((r & 7) << 3)] = val;
        else    thbuf[r][colg ^ ((r & 7) << 3)] = val;
      }
    }
    __syncthreads();  // B2
    // P2a: gate waves: h-part MFMAs; x-waves: finalize x_s from peers' th
    f32x4 acc[4];
    if (isgate) {
      bf16x8 afr[8];
#pragma unroll
      for (int kt = 0; kt < 8; ++kt)
        afr[kt] = *reinterpret_cast<const bf16x8*>(&hbuf[c16][(kt * 32 + 8 * g4) ^ ((c16 & 7) << 3)]);
#pragma unroll
      for (int gi = 0; gi < 4; ++gi) {
        f32x4 a = {biasv[gi], biasv[gi], biasv[gi], biasv[gi]};
#pragma unroll
        for (int kk = 0; kk < 4; ++kk)
          a = MFMA(afr[4 + kk], __builtin_bit_cast(bf16x8, wr[gi][kk]), a, 0, 0, 0);
#pragma unroll
        for (int kt = 0; kt < 4; ++kt)
          a = MFMA(afr[kt],
                   *reinterpret_cast<const bf16x8*>(&wslb[((gi * 4 + cb) << 8) + (kt << 6) + l]),
                   a, 0, 0, 0);
        acc[gi] = a;
      }
    } else if (isx && s > 0) {
#pragma unroll
      for (int kt = 0; kt < 8; ++kt) {
        if ((kt >> 1) == p) continue;  // local kts already accumulated
        bf16x8 ta = *reinterpret_cast<const bf16x8*>(&thbuf[c16][(kt * 32 + 8 * g4) ^ ((c16 & 7) << 3)]);
        xacc = MFMA(ta, __builtin_bit_cast(bf16x8, wo[kt]), xacc, 0, 0, 0);
      }
      int f = jn * 16 + c16;
#pragma unroll
      for (int v = 0; v < 4; ++v) {
        int rr = r0 + v;
        xbuf[rr][f] = f2bf(xacc[v]);
        out[(g * 16 + rr) * (NF * SLEN) + f * SLEN + (s - 1)] = xacc[v];
      }
      xacc = (f32x4){bo, bo, bo, bo};
    }
    __syncthreads();  // B3: xbuf ready, hbuf reads done
    // P2b: gate waves: + x@W_ih, elementwise, publish h_{s+1}/th_{s+1}
    if (isgate) {
      bf16x8 xfr = *reinterpret_cast<const bf16x8*>(&xbuf[c16][8 * g4]);
#pragma unroll
      for (int gi = 0; gi < 4; ++gi) acc[gi] = MFMA(xfr, wih[gi], acc[gi], 0, 0, 0);
      int lc = cb * 16 + c16, col = p * 64 + lc;
      u16 hp[4], tp[4];
#pragma unroll
      for (int v = 0; v < 4; ++v) {
        float iv = acc[0][v], fv = acc[1][v], gv = acc[2][v], ov = acc[3][v];
        float cc = sigf(fv) * cst[v] + sigf(iv) * tanhf_(gv);
        cst[v] = cc;
        float hh = sigf(ov) * tanhf_(cc);
        float th = tanhf_(hh);
        int rr = r0 + v, sw = (rr & 7) << 3;
        hp[v] = f2bf(hh); tp[v] = f2bf(th);
        hbuf[rr][col ^ sw] = hp[v]; thbuf[rr][col ^ sw] = tp[v];
      }
      u64 hu = (u64)hp[0] | ((u64)hp[1] << 16) | ((u64)hp[2] << 32) | ((u64)hp[3] << 48);
      u64 tu = (u64)tp[0] | ((u64)tp[1] << 16) | ((u64)tp[2] << 32) | ((u64)tp[3] << 48);
      __hip_atomic_store(&hst[((u64)(g * 257 + s + 1) * 4 + p) * 256 + lc * 4 + g4], hu,
                         __ATOMIC_RELAXED, __HIP_MEMORY_SCOPE_AGENT);
      __hip_atomic_store(&th_ex[((g * 2 + ((s + 1) & 1)) * 4 + p) * 256 + lc * 4 + g4], tu,
                         __ATOMIC_RELAXED, __HIP_MEMORY_SCOPE_AGENT);
    }
    asm volatile("s_waitcnt vmcnt(0)" ::: "memory");
    __syncthreads();  // B4
    if (tid == 0)
      __hip_atomic_fetch_add(&mycnt[s + 1], 1u, __ATOMIC_RELEASE, __HIP_MEMORY_SCOPE_AGENT);
    // P3: x-waves: local-K part of x_{s+1}
    if (isx) {
#pragma unroll
      for (int d = 0; d < 2; ++d) {
        int kt = 2 * p + d;
        bf16x8 ta = *reinterpret_cast<const bf16x8*>(&thbuf[c16][(kt * 32 + 8 * g4) ^ ((c16 & 7) << 3)]);
        xacc = MFMA(ta, __builtin_bit_cast(bf16x8, wo[kt]), xacc, 0, 0, 0);
      }
    }
  }

  // ---- tail: finalize x_256 -> mu col 255 ----
  if (tid == 0) {
    while (__hip_atomic_load(&mycnt[256], __ATOMIC_ACQUIRE, __HIP_MEMORY_SCOPE_AGENT) < 4u)
      __builtin_amdgcn_s_sleep(1);
  }
  __syncthreads();
#pragma unroll
  for (int k = 0; k < 2; ++k) {
    int idx = k * 512 + tid;
    if (idx < 768) {
      int peer = idx >> 8, cr = idx & 255;
      int pp = (p + 1 + peer) & 3;
      u64 v = __hip_atomic_load(&th_ex[((g * 2 + 0) * 4 + pp) * 256 + cr],
                                __ATOMIC_RELAXED, __HIP_MEMORY_SCOPE_AGENT);
      int colg = pp * 64 + (cr >> 2), rb = (cr & 3) * 4;
#pragma unroll
      for (int e = 0; e < 4; ++e) {
        int r = rb + e;
        thbuf[r][colg ^ ((r & 7) << 3)] = (u16)(v >> (16 * e));
      }
    }
  }
  __syncthreads();
  if (isx) {
#pragma unroll
    for (int kt = 0; kt < 8; ++kt) {
      if ((kt >> 1) == p) continue;
      bf16x8 ta = *reinterpret_cast<const bf16x8*>(&thbuf[c16][(kt * 32 + 8 * g4) ^ ((c16 & 7) << 3)]);
      xacc = MFMA(ta, __builtin_bit_cast(bf16x8, wo[kt]), xacc, 0, 0, 0);
    }
    int f = jn * 16 + c16;
#pragma unroll
    for (int v = 0; v < 4; ++v)
      out[(g * 16 + r0 + v) * (NF * SLEN) + f * SLEN + 255] = xacc[v];
  }
}

// ---------------- sigma: 64 WGs x 16 rows, K=65536 ----------------
__global__ __launch_bounds__(512) void sigma_gemm(
    const uint4* __restrict__ hstv, const uint4* __restrict__ ws,
    const float* __restrict__ b_sig, float* __restrict__ out) {
  __shared__ __align__(16) u16 st[8][16][256];   // 64KB, per-wave staging (swizzled)
  __shared__ float sred[8][16][32];              // 16KB

  const int tid = threadIdx.x, w = tid >> 6, l = tid & 63;
  const int c16 = l & 15, g4 = l >> 4;
  const int g = blockIdx.x;

  f32x4 a0 = {0.f, 0.f, 0.f, 0.f}, a1 = {0.f, 0.f, 0.f, 0.f};
  for (int i = 0; i < 32; ++i) {
    int ss = w * 32 + 1 + i;
    // stage hst[g][ss][*][*][*] -> st[w] (transposed to [row][h])
#pragma unroll
    for (int pp = 0; pp < 4; ++pp) {
      int base = ((g * 257 + ss) * 4 + pp) * 128 + l * 2;  // uint4 units
      uint4 q0 = hstv[base], q1 = hstv[base + 1];
      int h = pp * 64 + l;
      unsigned int qq[8] = {q0.x, q0.y, q0.z, q0.w, q1.x, q1.y, q1.z, q1.w};
#pragma unroll
      for (int r = 0; r < 16; ++r) {
        u16 val = (u16)(qq[r >> 1] >> (16 * (r & 1)));
        st[w][r][h ^ ((r & 7) << 3)] = val;
      }
    }
    __builtin_amdgcn_s_waitcnt(0);  // lgkm drain before read (compiler also inserts)
    const uint4* bp = ws + WT_O + ((ss - 1) * 2) * 8 * 64 + l;
#pragma unroll
    for (int kt = 0; kt < 8; ++kt) {
      bf16x8 av = *reinterpret_cast<const bf16x8*>(&st[w][c16][(kt * 32 + 8 * g4) ^ ((c16 & 7) << 3)]);
      a0 = MFMA(av, *reinterpret_cast<const bf16x8*>(bp + kt * 64), a0, 0, 0, 0);
      a1 = MFMA(av, *reinterpret_cast<const bf16x8*>(bp + (8 + kt) * 64), a1, 0, 0, 0);
    }
  }
#pragma unroll
  for (int v = 0; v < 4; ++v) {
    sred[w][g4 * 4 + v][c16] = a0[v];
    sred[w][g4 * 4 + v][16 + c16] = a1[v];
  }
  __syncthreads();
  int b = tid >> 5, f = tid & 31;
  if (b < 16) {
    float acc = b_sig[f];
#pragma unroll
    for (int ww = 0; ww < 8; ++ww) acc += sred[ww][b][f];
    float sp = fmaxf(acc, 0.0f) + log1pf(__expf(-fabsf(acc)));
    out[BATCH * NF * SLEN + (g * 16 + b) * NF + f] = sp;
  }
}

extern "C" void kernel_launch(void* const* d_in, const int* in_sizes, int n_in,
                              void* d_out, int out_size, void* d_ws, size_t ws_size,
                              hipStream_t stream) {
  (void)in_sizes; (void)n_in; (void)out_size; (void)ws_size;
  const float* z     = (const float*)d_in[0];
  const float* W_lat = (const float*)d_in[1];
  const float* b_lat = (const float*)d_in[2];
  const float* W_ih  = (const float*)d_in[3];
  const float* b_ih  = (const float*)d_in[4];
  const float* W_hh  = (const float*)d_in[5];
  const float* b_hh  = (const float*)d_in[6];
  const float* W_out = (const float*)d_in[7];
  const float* b_out = (const float*)d_in[8];
  const float* W_sig = (const float*)d_in[9];
  const float* b_sig = (const float*)d_in[10];
  char* wsb = (char*)d_ws;
  uint4* ws = (uint4*)wsb;
  u64* th_ex = (u64*)(wsb + THEX_BYTE);
  unsigned int* cnt = (unsigned int*)(wsb + CNT_BYTE);
  u64* hst = (u64*)(wsb + HST_BYTE);
  float* out = (float*)d_out;

  prep_pack<<<(PREP1_N + 255) / 256, 256, 0, stream>>>(W_hh, W_ih, W_out, W_lat, ws);
  prep_wt<<<1024, 256, 0, stream>>>(W_sig, ws);
  prep_zero<<<(CNT_N + 255) / 256, 256, 0, stream>>>(cnt);
  lstm_scan<<<256, 512, 0, stream>>>(z, b_lat, b_ih, b_hh, b_out, ws, th_ex, cnt, hst, out);
  sigma_gemm<<<64, 512, 0, stream>>>((const uint4*)(wsb + HST_BYTE), ws, b_sig, out);
}